// Round 8
// baseline (387.085 us; speedup 1.0000x reference)
//
#include <hip/hip_runtime.h>
#include <stdint.h>

#define XH   256
#define NCLS 104

typedef _Float16 half2v __attribute__((ext_vector_type(2)));
typedef _Float16 half4v __attribute__((ext_vector_type(4)));
typedef _Float16 half8v __attribute__((ext_vector_type(8)));
typedef __attribute__((ext_vector_type(4))) float floatx4;

__device__ __forceinline__ void gll16(const void* g, void* l) {
    __builtin_amdgcn_global_load_lds(
        (const __attribute__((address_space(1))) unsigned*)g,
        (__attribute__((address_space(3))) unsigned*)l, 16, 0, 0);
}
__device__ __forceinline__ float fdot2f(half2v a, half2v b, float c) {
#if __has_builtin(__builtin_amdgcn_fdot2)
    return __builtin_amdgcn_fdot2(a, b, c, false);
#else
    return c + (float)a[0] * (float)b[0] + (float)a[1] * (float)b[1];
#endif
}
// 16B-granule XOR swizzle within 64B groups: 2-way-max LDS bank aliasing
__device__ __forceinline__ int MF(int x) { return (x + (x >> 2)) & 3; }

// W16 sections (element offsets, VQ = vocab*256):
//   0:Yl   VQ:Yr   2VQ:Ym=(Yl+Yr)/2   3VQ:Yt(+b_conv)   4VQ:embf

// ---------------------------------------------------------------------------
__global__ __launch_bounds__(256)
void k_prep(const float* __restrict__ Wl, const float* __restrict__ Wr,
            const float* __restrict__ Wt,
            const int* __restrict__ edge_src, const int* __restrict__ edge_dst,
            const float* __restrict__ alpha, const int* __restrict__ node_type,
            _Float16* __restrict__ Btw, int2* __restrict__ epk,
            int* __restrict__ row_start, int VQ, int E) {
    int idx = blockIdx.x * 256 + threadIdx.x;
    if (idx < 3 * XH * XH) {
        int n = idx >> 8, k = idx & 255;
        int m, c;
        if (n < 512) { m = n & 1; c = n >> 1; }
        else         { m = 2;     c = n - 512; }
        const float* W = (m == 0) ? Wl : (m == 1) ? Wr : Wt;
        Btw[idx] = (_Float16)W[k * XH + c];
        return;
    }
    idx -= 3 * XH * XH;
    if (idx < E) {
        int s  = edge_src[idx];
        float a = alpha[idx];
        int ts = node_type[s];
        int x;
        half2v w;
        if      (a == 0.0f) { x = ts * 256;          w = half2v{1.0f16, 0.0f16}; }
        else if (a == 1.0f) { x = VQ + ts * 256;     w = half2v{1.0f16, 0.0f16}; }
        else if (a == 0.5f) { x = 2 * VQ + ts * 256; w = half2v{1.0f16, 0.0f16}; }
        else { x = (ts * 256) | 1; w = half2v{(_Float16)(1.f - a), (_Float16)a}; }
        int2 p;
        p.x = x;
        p.y = __builtin_bit_cast(int, w);
        epk[idx] = p;
        int d = edge_dst[idx];
        if (idx == 0 || edge_dst[idx - 1] != d) row_start[d] = idx;
    }
}

// ---------------------------------------------------------------------------
// Y = f16(emb) @ [Wl|Wr|Wt], operand-swapped MFMA; coalesced section stores.
// (unchanged from round 7)
// ---------------------------------------------------------------------------
__global__ __launch_bounds__(512, 4)
void k_main(const float* __restrict__ emb, const _Float16* __restrict__ Btw,
            const float* __restrict__ b_conv, _Float16* __restrict__ W16, int VQ) {
    __shared__ __align__(16) _Float16 Ab[32 * 256];
    __shared__ __align__(16) _Float16 Bb[768 * 32];

    const int tid  = threadIdx.x;
    const int lane = tid & 63;
    const int wv   = tid >> 6;
    const int quad = lane >> 4;
    const int l15  = lane & 15;
    const int m0   = blockIdx.x * 32;

    {
        int row = tid >> 4;
        int cg  = tid & 15;
        const float* ga = &emb[(size_t)(m0 + row) * XH + cg * 16];
        floatx4 f0 = *(const floatx4*)ga;
        floatx4 f1 = *(const floatx4*)(ga + 4);
        floatx4 f2 = *(const floatx4*)(ga + 8);
        floatx4 f3 = *(const floatx4*)(ga + 12);
        half8v h0, h1;
        #pragma unroll
        for (int i = 0; i < 4; i++) {
            h0[i] = (_Float16)f0[i]; h0[4 + i] = (_Float16)f1[i];
            h1[i] = (_Float16)f2[i]; h1[4 + i] = (_Float16)f3[i];
        }
        int g0 = cg * 2, g1 = cg * 2 + 1;
        *(half8v*)&Ab[row * 256 + (g0 >> 2) * 32 + ((g0 & 3) ^ MF(row & 15)) * 8] = h0;
        *(half8v*)&Ab[row * 256 + (g1 >> 2) * 32 + ((g1 & 3) ^ MF(row & 15)) * 8] = h1;
        _Float16* ep = &W16[(size_t)4 * VQ + (size_t)(m0 + row) * 256 + cg * 16];
        *(half8v*)ep = h0;
        *(half8v*)(ep + 8) = h1;
    }

    auto stageB = [&](int kc) {
        #pragma unroll
        for (int i = 0; i < 6; i++) {
            int grp = wv * 6 + i;
            int row = grp * 16 + (lane >> 2);
            int bd  = (lane & 3) ^ MF(row & 15);
            gll16((const char*)Btw + (size_t)row * 512 + kc * 64 + bd * 16,
                  (char*)Bb + grp * 1024);
        }
    };
    stageB(0);

    floatx4 acc[6][2];
    #pragma unroll
    for (int i = 0; i < 6; i++)
        #pragma unroll
        for (int j = 0; j < 2; j++) acc[i][j] = floatx4{0.f, 0.f, 0.f, 0.f};

    const int nbase = wv * 96;
    for (int kc = 0; kc < 8; kc++) {
        __syncthreads();
        half8v af[6], bf[2];
        #pragma unroll
        for (int nt = 0; nt < 6; nt++) {
            int row = nbase + nt * 16 + l15;
            af[nt] = *(const half8v*)&Bb[row * 32 + ((quad ^ MF(l15)) * 8)];
        }
        #pragma unroll
        for (int mt = 0; mt < 2; mt++) {
            int row = mt * 16 + l15;
            bf[mt] = *(const half8v*)&Ab[row * 256 + kc * 32 + ((quad ^ MF(l15)) * 8)];
        }
        __syncthreads();
        if (kc < 7) stageB(kc + 1);
        #pragma unroll
        for (int nt = 0; nt < 6; nt++)
            #pragma unroll
            for (int mt = 0; mt < 2; mt++)
                acc[nt][mt] = __builtin_amdgcn_mfma_f32_16x16x32_f16(af[nt], bf[mt], acc[nt][mt], 0, 0, 0);
    }

    #pragma unroll
    for (int nt = 0; nt < 6; nt++) {
        #pragma unroll
        for (int mt = 0; mt < 2; mt++) {
            int m  = mt * 16 + l15;
            int n0 = nbase + nt * 16 + quad * 4;
            half4v hv;
            #pragma unroll
            for (int r = 0; r < 4; r++) hv[r] = (_Float16)acc[nt][mt][r];
            int gs = (n0 >> 2) ^ (m & 7);
            *(half4v*)((char*)Bb + (size_t)m * 1536 + gs * 8) = hv;
        }
    }
    __syncthreads();

    #pragma unroll
    for (int it = 0; it < 4; it++) {
        int u = it * 512 + tid;
        int m = u >> 6, ns = u & 63;
        int q0 = ((ns * 8) >> 2) ^ (m & 7);
        int q1 = (((ns * 8) >> 2) + 1) ^ (m & 7);
        half4v v0 = *(const half4v*)((const char*)Bb + (size_t)m * 1536 + q0 * 8);
        half4v v1 = *(const half4v*)((const char*)Bb + (size_t)m * 1536 + q1 * 8);
        float l0 = (float)v0[0], r0 = (float)v0[1], l1 = (float)v0[2], r1 = (float)v0[3];
        float l2 = (float)v1[0], r2 = (float)v1[1], l3 = (float)v1[2], r3 = (float)v1[3];
        half4v yl = { (_Float16)l0, (_Float16)l1, (_Float16)l2, (_Float16)l3 };
        half4v yr = { (_Float16)r0, (_Float16)r1, (_Float16)r2, (_Float16)r3 };
        half4v ym = { (_Float16)(0.5f * (l0 + r0)), (_Float16)(0.5f * (l1 + r1)),
                      (_Float16)(0.5f * (l2 + r2)), (_Float16)(0.5f * (l3 + r3)) };
        size_t ro = (size_t)(m0 + m) * 256 + ns * 4;
        *(half4v*)&W16[ro]          = yl;
        *(half4v*)&W16[VQ + ro]     = yr;
        *(half4v*)&W16[2 * VQ + ro] = ym;
    }
    #pragma unroll
    for (int it = 0; it < 2; it++) {
        int u = it * 512 + tid;
        int m = u >> 5, ns = u & 31;
        int n0 = 512 + ns * 8;
        int q0 = (n0 >> 2) ^ (m & 7);
        int q1 = ((n0 >> 2) + 1) ^ (m & 7);
        half4v v0 = *(const half4v*)((const char*)Bb + (size_t)m * 1536 + q0 * 8);
        half4v v1 = *(const half4v*)((const char*)Bb + (size_t)m * 1536 + q1 * 8);
        floatx4 b0 = *(const floatx4*)&b_conv[ns * 8];
        floatx4 b1 = *(const floatx4*)&b_conv[ns * 8 + 4];
        half8v o;
        #pragma unroll
        for (int i = 0; i < 4; i++) {
            o[i]     = (_Float16)((float)v0[i] + b0[i]);
            o[4 + i] = (_Float16)((float)v1[i] + b1[i]);
        }
        *(half8v*)&W16[(size_t)3 * VQ + (size_t)(m0 + m) * 256 + ns * 8] = o;
    }
}

// ---------------------------------------------------------------------------
// One 1024-thread block per graph; 16 waves x 2 half-wave slots = 32 slots.
// Each 32-lane half owns one node (8 f16/lane, 16B loads); slot s owns nodes
// s, s+32, ... Edge loop: 2-edge unroll per half, dual-descriptor pipeline.
// ---------------------------------------------------------------------------
__global__ __launch_bounds__(1024, 8)
void k_graph(const int* __restrict__ nty, const int* __restrict__ cc,
             const _Float16* __restrict__ W16,
             const int2* __restrict__ epk, const int* __restrict__ row_start,
             const float* __restrict__ gate_w, const float* __restrict__ gate_b,
             const float* __restrict__ cls_w, const float* __restrict__ cls_b,
             float* __restrict__ out, int PER, int VQ) {
    const int g    = blockIdx.x;
    const int tid  = threadIdx.x;
    const int lane = tid & 63;
    const int l32  = lane & 31;
    const int slot = (tid >> 6) * 2 + (lane >> 5);   // 0..31
    const int base = g * PER;

    __shared__ float pw[32 * XH];     // 32 KB
    __shared__ float ds[32];
    __shared__ float pooled[XH];

    float gw8[8];
    #pragma unroll
    for (int i = 0; i < 8; i++) gw8[i] = gate_w[8 * l32 + i];
    const float gb = gate_b[0];

    float acc8[8] = {0.f, 0.f, 0.f, 0.f, 0.f, 0.f, 0.f, 0.f};
    float dsum = 0.f;

    // prime node state for the first iteration
    int vg = base + slot;
    int c  = cc[vg];
    int tv = nty[vg];
    int rs = (c > 0) ? row_start[vg] : 0;
    int2 pd0 = epk[rs];
    int2 pd1 = epk[rs + (c > 1 ? 1 : 0)];

    for (int v = slot; v < PER; v += 32) {
        // prefetch next node's metadata + first two edge descriptors
        const bool has = (v + 32 < PER);
        const int vns = has ? vg + 32 : vg;
        int cn  = has ? cc[vns] : 0;
        int tvn = nty[vns];
        int rsn = (has && cn > 0) ? row_start[vns] : 0;
        int2 pdn0 = epk[rsn];
        int2 pdn1 = epk[rsn + (cn > 1 ? 1 : 0)];

        // yt: Yt(+bias) row for internal, embf row for leaf (same load site)
        half8v yt = *(const half8v*)&W16[(size_t)(c == 0 ? 4 : 3) * VQ + (size_t)tv * 256 + 8 * l32];

        float s8[8] = {0.f, 0.f, 0.f, 0.f, 0.f, 0.f, 0.f, 0.f};
        int e = rs;
        const int e1 = rs + c;
        int2 p0 = pd0, p1 = pd1;
        while (__any(e < e1)) {
            if (e < e1) {
                int2 np0 = epk[min(e + 2, e1 - 1)];
                int2 np1 = epk[min(e + 3, e1 - 1)];
                int off0 = p0.x & ~1, d0 = (p0.x & 1) ? VQ : 0;
                half8v a0 = *(const half8v*)&W16[(size_t)off0 + 8 * l32];
                half8v b0 = *(const half8v*)&W16[(size_t)(off0 + d0) + 8 * l32];
                half2v w0 = __builtin_bit_cast(half2v, p0.y);
                if (e + 1 < e1) {
                    int off1 = p1.x & ~1, d1 = (p1.x & 1) ? VQ : 0;
                    half8v a1 = *(const half8v*)&W16[(size_t)off1 + 8 * l32];
                    half8v b1 = *(const half8v*)&W16[(size_t)(off1 + d1) + 8 * l32];
                    half2v w1 = __builtin_bit_cast(half2v, p1.y);
                    #pragma unroll
                    for (int i = 0; i < 8; i++)
                        s8[i] = fdot2f(half2v{a0[i], b0[i]}, w0, s8[i]);
                    #pragma unroll
                    for (int i = 0; i < 8; i++)
                        s8[i] = fdot2f(half2v{a1[i], b1[i]}, w1, s8[i]);
                } else {
                    #pragma unroll
                    for (int i = 0; i < 8; i++)
                        s8[i] = fdot2f(half2v{a0[i], b0[i]}, w0, s8[i]);
                }
                p0 = np0; p1 = np1;
                e += 2;
            }
        }

        float h8[8];
        if (c == 0) {
            #pragma unroll
            for (int i = 0; i < 8; i++) h8[i] = (float)yt[i];
        } else {
            #pragma unroll
            for (int i = 0; i < 8; i++) h8[i] = fmaxf(s8[i] + (float)yt[i], 0.f);
        }

        float sg = 0.f;
        #pragma unroll
        for (int i = 0; i < 8; i++) sg += h8[i] * gw8[i];
        #pragma unroll
        for (int o = 1; o < 32; o <<= 1) sg += __shfl_xor(sg, o);
        float ew = __expf(sg + gb);
        dsum += ew;
        #pragma unroll
        for (int i = 0; i < 8; i++) acc8[i] += ew * h8[i];

        c = cn; tv = tvn; rs = rsn; pd0 = pdn0; pd1 = pdn1; vg = vns;
    }

    #pragma unroll
    for (int i = 0; i < 8; i++) pw[slot * XH + 8 * l32 + i] = acc8[i];
    if (l32 == 0) ds[slot] = dsum;
    __syncthreads();

    if (tid < XH) {
        float p = 0.f, d = 0.f;
        #pragma unroll
        for (int w = 0; w < 32; w++) p += pw[w * XH + tid];
        #pragma unroll
        for (int w = 0; w < 32; w++) d += ds[w];
        pooled[tid] = p / d;
    }
    __syncthreads();

    if (tid < NCLS) {
        float o = cls_b[tid];
        #pragma unroll 8
        for (int k = 0; k < XH; k++) o += pooled[k] * cls_w[k * NCLS + tid];
        out[g * NCLS + tid] = o;
    }
}

// ---------------------------------------------------------------------------
extern "C" void kernel_launch(void* const* d_in, const int* in_sizes, int n_in,
                              void* d_out, int out_size, void* d_ws, size_t ws_size,
                              hipStream_t stream) {
    const int*   node_type   = (const int*)d_in[0];
    const int*   edge_src    = (const int*)d_in[1];
    const int*   edge_dst    = (const int*)d_in[2];
    const float* alpha       = (const float*)d_in[3];
    const int*   child_count = (const int*)d_in[4];
    // d_in[5] graph_ids unused: nodes of a graph are contiguous
    const float* emb         = (const float*)d_in[6];
    const float* Wl          = (const float*)d_in[7];
    const float* Wr          = (const float*)d_in[8];
    const float* Wt          = (const float*)d_in[9];
    const float* b_conv      = (const float*)d_in[10];
    const float* gate_w      = (const float*)d_in[11];
    const float* gate_b      = (const float*)d_in[12];
    const float* cls_w       = (const float*)d_in[13];
    const float* cls_b       = (const float*)d_in[14];

    const int N     = in_sizes[0];
    const int E     = in_sizes[1];
    const int vocab = in_sizes[6] / XH;
    const int G     = out_size / NCLS;
    const int PER   = N / G;
    const int VQ    = vocab * 256;

    _Float16* W16 = (_Float16*)d_ws;                          // 5*VQ f16
    _Float16* Btw = W16 + (size_t)5 * VQ;                     // 768*256 f16
    int2*     epk = (int2*)(Btw + 3 * XH * XH);               // E * 8B
    int*      row_start = (int*)(epk + E);                    // N * 4B

    hipLaunchKernelGGL(k_prep, dim3((3 * XH * XH + E + 255) / 256), dim3(256), 0, stream,
                       Wl, Wr, Wt, edge_src, edge_dst, alpha, node_type,
                       Btw, epk, row_start, VQ, E);

    hipLaunchKernelGGL(k_main, dim3(vocab / 32), dim3(512), 0, stream,
                       emb, Btw, b_conv, W16, VQ);

    hipLaunchKernelGGL(k_graph, dim3(G), dim3(1024), 0, stream,
                       node_type, child_count, W16, epk, row_start,
                       gate_w, gate_b, cls_w, cls_b, (float*)d_out, PER, VQ);
}